// Round 11
// baseline (93.722 us; speedup 1.0000x reference)
//
#include <hip/hip_runtime.h>

#define MTOK 8192   // B*S tokens
#define ED   1024   // E == D == 1024

typedef short s16x8 __attribute__((ext_vector_type(8)));
typedef float f32x4 __attribute__((ext_vector_type(4)));
typedef int   i32x4 __attribute__((ext_vector_type(4)));
typedef unsigned short u16x4 __attribute__((ext_vector_type(4)));

__device__ __forceinline__ int cvtpk(float a, float b) {
    int r;
    asm("v_cvt_pk_bf16_f32 %0, %1, %2" : "=v"(r) : "v"(a), "v"(b));
    return r;
}

// pack f0|f1 (8 fp32) -> 8 bf16 hi + 8 bf16 lo (exact residual), 16B each
__device__ __forceinline__ void cvt_write(void* dstHi, void* dstLo,
                                          const float4 f0, const float4 f1) {
    i32x4 h, l;
    h[0] = cvtpk(f0.x, f0.y); h[1] = cvtpk(f0.z, f0.w);
    h[2] = cvtpk(f1.x, f1.y); h[3] = cvtpk(f1.z, f1.w);
    l[0] = cvtpk(f0.x - __builtin_bit_cast(float, h[0] << 16),
                 f0.y - __builtin_bit_cast(float, h[0] & 0xffff0000));
    l[1] = cvtpk(f0.z - __builtin_bit_cast(float, h[1] << 16),
                 f0.w - __builtin_bit_cast(float, h[1] & 0xffff0000));
    l[2] = cvtpk(f1.x - __builtin_bit_cast(float, h[2] << 16),
                 f1.y - __builtin_bit_cast(float, h[2] & 0xffff0000));
    l[3] = cvtpk(f1.z - __builtin_bit_cast(float, h[3] << 16),
                 f1.w - __builtin_bit_cast(float, h[3] & 0xffff0000));
    *(i32x4*)dstHi = h;
    *(i32x4*)dstLo = l;
}

// ---------------- W -> fragment-major bf16 hi/lo ----------------
// Bfrag[rowblk 0..63][kstep 0..31][lane 0..63][8]:
//   lane (fg=l>>4, fr=l&15) holds W[rowblk*16+fr][kstep*32+fg*8 .. +8]
// == exactly the bytes the r10 LDS path delivered per lane (sg/pg algebra).
__global__ __launch_bounds__(256) void wfrag_kernel(
        const float* __restrict__ W,
        unsigned short* __restrict__ Bhi, unsigned short* __restrict__ Blo) {
    const int task = blockIdx.x * 4 + (threadIdx.x >> 6);   // 0..2047
    const int lane = threadIdx.x & 63;
    const int rowblk = task >> 5;
    const int kstep  = task & 31;
    const float* src = W + (size_t)(rowblk * 16 + (lane & 15)) * ED
                         + kstep * 32 + (lane >> 4) * 8;
    const float4 f0 = *(const float4*)src;
    const float4 f1 = *(const float4*)(src + 4);
    const size_t o = ((size_t)task * 64 + lane) * 8;
    cvt_write(&Bhi[o], &Blo[o], f0, f1);
}

// ---------------- MFMA split GEMM: C[M,E] = X[M,D] * W[E,D]^T ----------------
// A: global fp32 -> regs -> cvt -> ds_write (write-late), LDS = 2 x 16KB A only.
// B: fragment-major global, loaded straight to registers, double-buffered one
// K-step ahead (L2-resident W; latency hidden under MFMA). No vmcnt in drain;
// barrier only orders the A double-buffer. LDS traffic per block-step 96->48KB.
__global__ __launch_bounds__(256, 2) void gemm_mfma_split_kernel(
        const float* __restrict__ Xf,
        const unsigned short* __restrict__ Bhi, const unsigned short* __restrict__ Blo,
        float* __restrict__ C) {
    __shared__ __align__(16) unsigned char smem[2 * 16384];  // 32 KB: A hi/lo dbuf

    // bm-major XCD swizzle
    const int bid = blockIdx.x;
    const int xcd = bid & 7;
    const int j   = bid >> 3;
    const int bm  = xcd * 8 + (j >> 3);
    const int bn  = j & 7;

    const int tid  = threadIdx.x;
    const int lane = tid & 63;
    const int wid  = tid >> 6;

    // A staging map (proven r4/r10): wave stages rows wid*32..+31
    const int srow = lane >> 2;
    const int sg   = (lane & 3) ^ ((lane >> 3) & 3);
    const float* gA = Xf + (size_t)(bm * 128 + wid * 32 + srow) * ED + sg * 8;

    float4 fA0, fA1, fA2, fA3;
#define ALOAD(kk)                                                    \
    fA0 = *(const float4*)(gA + (kk));                               \
    fA1 = *(const float4*)(gA + (kk) + 4);                           \
    fA2 = *(const float4*)(gA + (kk) + 16 * 1024);                   \
    fA3 = *(const float4*)(gA + (kk) + 16 * 1024 + 4);

#define AWRITE(BOFF)                                                             \
    cvt_write(smem + (BOFF) + (2 * wid) * 1024 + lane * 16,                      \
              smem + (BOFF) + 8192 + (2 * wid) * 1024 + lane * 16, fA0, fA1);    \
    cvt_write(smem + (BOFF) + (2 * wid + 1) * 1024 + lane * 16,                  \
              smem + (BOFF) + 8192 + (2 * wid + 1) * 1024 + lane * 16, fA2, fA3);

    // fragment read setup
    const int wm = wid >> 1, wn = wid & 1;
    const int fr = lane & 15, fg = lane >> 4;
    const int pg = fg ^ ((fr >> 1) & 3);
    const int aoff = (wm * 64 + fr) * 32 + pg * 8;   // elems in Ahi/Alo (8KB ea)

    // B fragment pointers: rowblk = bn*8 + wn*4 + i; elem = rowblk*16384 + t*512 + lane*8
    const unsigned short* gBh = Bhi + (size_t)(bn * 8 + wn * 4) * 16384 + lane * 8;
    const unsigned short* gBl = Blo + (size_t)(bn * 8 + wn * 4) * 16384 + lane * 8;

    s16x8 bh0[4], bl0[4], bh1[4], bl1[4];
#define BLOAD(S, T)                                                  \
    _Pragma("unroll")                                                \
    for (int i = 0; i < 4; ++i) {                                    \
        bh##S[i] = *(const s16x8*)(gBh + i * 16384 + (T) * 512);     \
        bl##S[i] = *(const s16x8*)(gBl + i * 16384 + (T) * 512);     \
    }

    f32x4 acc[4][4] = {};

#define STEP(T, BUFOFF, S, SN)                                                   \
    {                                                                            \
        if ((T) < 31) { ALOAD(((T) + 1) * 32); BLOAD(SN, (T) + 1); }             \
        const unsigned short* Ah = (const unsigned short*)(smem + (BUFOFF));     \
        const unsigned short* Al = Ah + 4096;                                    \
        s16x8 ah[4], al[4];                                                      \
        _Pragma("unroll")                                                        \
        for (int i = 0; i < 4; ++i) {                                            \
            ah[i] = *(const s16x8*)&Ah[aoff + i * 512];                          \
            al[i] = *(const s16x8*)&Al[aoff + i * 512];                          \
        }                                                                        \
        _Pragma("unroll")                                                        \
        for (int i = 0; i < 4; ++i)                                              \
            _Pragma("unroll")                                                    \
            for (int jj = 0; jj < 4; ++jj) {                                     \
                acc[i][jj] = __builtin_amdgcn_mfma_f32_16x16x32_bf16(ah[i], bh##S[jj], acc[i][jj], 0, 0, 0); \
                acc[i][jj] = __builtin_amdgcn_mfma_f32_16x16x32_bf16(ah[i], bl##S[jj], acc[i][jj], 0, 0, 0); \
                acc[i][jj] = __builtin_amdgcn_mfma_f32_16x16x32_bf16(al[i], bh##S[jj], acc[i][jj], 0, 0, 0); \
            }                                                                    \
        if ((T) < 31) AWRITE((BUFOFF) ^ 16384);                                  \
        asm volatile("s_waitcnt lgkmcnt(0)" ::: "memory");                       \
        __builtin_amdgcn_s_barrier();                                            \
    }

    // prologue: tile 0 -> buf0 (A) + set0 (B)
    ALOAD(0);
    BLOAD(0, 0);
    AWRITE(0);
    asm volatile("s_waitcnt lgkmcnt(0)" ::: "memory");
    __builtin_amdgcn_s_barrier();

    for (int t2 = 0; t2 < 32; t2 += 2) {
        STEP(t2,     0,     0, 1)
        STEP(t2 + 1, 16384, 1, 0)
    }
#undef STEP
#undef BLOAD
#undef AWRITE
#undef ALOAD

    const int crow = bm * 128 + wm * 64 + fg * 4;
    const int ccol = bn * 128 + wn * 64 + fr;
#pragma unroll
    for (int i = 0; i < 4; ++i)
#pragma unroll
        for (int jj = 0; jj < 4; ++jj)
#pragma unroll
            for (int r = 0; r < 4; ++r)
                C[(size_t)(crow + i * 16 + r) * ED + ccol + jj * 16] = acc[i][jj][r];
}

// ---------------- fp32 fallback GEMM ----------------
#define BM 128
#define BN 128
#define BK 32
#define LDA (BM + 4)
#define LDB (BN + 4)

__global__ __launch_bounds__(256) void gemm_logits_kernel(const float* __restrict__ X,
                                                          const float* __restrict__ W,
                                                          float* __restrict__ C) {
    __shared__ float As[BK][LDA];
    __shared__ float Bs[BK][LDB];
    const int bm  = blockIdx.y * BM;
    const int bn  = blockIdx.x * BN;
    const int tid = threadIdx.x;
    const int tx  = tid & 15;
    const int ty  = tid >> 4;
    const int lr  = tid >> 3;
    const int lc  = (tid & 7) << 2;

    float acc[8][8];
#pragma unroll
    for (int i = 0; i < 8; ++i)
#pragma unroll
        for (int j = 0; j < 8; ++j) acc[i][j] = 0.f;

    for (int k0 = 0; k0 < ED; k0 += BK) {
#pragma unroll
        for (int i = 0; i < 4; ++i) {
            const int r = lr + i * 32;
            float4 va = *(const float4*)&X[(size_t)(bm + r) * ED + k0 + lc];
            As[lc + 0][r] = va.x; As[lc + 1][r] = va.y;
            As[lc + 2][r] = va.z; As[lc + 3][r] = va.w;
            float4 vb = *(const float4*)&W[(size_t)(bn + r) * ED + k0 + lc];
            Bs[lc + 0][r] = vb.x; Bs[lc + 1][r] = vb.y;
            Bs[lc + 2][r] = vb.z; Bs[lc + 3][r] = vb.w;
        }
        __syncthreads();
#pragma unroll
        for (int kk = 0; kk < BK; ++kk) {
            float a[8], b[8];
            *(float4*)&a[0] = *(const float4*)&As[kk][ty * 8];
            *(float4*)&a[4] = *(const float4*)&As[kk][ty * 8 + 4];
            *(float4*)&b[0] = *(const float4*)&Bs[kk][tx * 8];
            *(float4*)&b[4] = *(const float4*)&Bs[kk][tx * 8 + 4];
#pragma unroll
            for (int i = 0; i < 8; ++i)
#pragma unroll
                for (int j = 0; j < 8; ++j)
                    acc[i][j] = fmaf(a[i], b[j], acc[i][j]);
        }
        __syncthreads();
    }
#pragma unroll
    for (int i = 0; i < 8; ++i) {
        const int r = bm + ty * 8 + i;
        float4* dst = (float4*)&C[(size_t)r * ED + bn + tx * 8];
        dst[0] = make_float4(acc[i][0], acc[i][1], acc[i][2], acc[i][3]);
        dst[1] = make_float4(acc[i][4], acc[i][5], acc[i][6], acc[i][7]);
    }
}

__device__ __forceinline__ bool better(float v, int i, float bv, int bi) {
    return (v > bv) || (v == bv && i < bi);
}

// ------------- one wave per token, barrier-free softmax/top2/y -------------
__global__ __launch_bounds__(256, 8) void softmax_wave_kernel(
        const float* __restrict__ X, float* __restrict__ OUT,
        float* __restrict__ partial, int* __restrict__ counts) {
    __shared__ float L[4 * 1024];
    const int tid  = threadIdx.x;
    const int lane = tid & 63;
    const int w    = tid >> 6;
    const int t    = blockIdx.x * 4 + w;          // token

    const float4* row4 = (const float4*)&OUT[(size_t)t * ED];
    float4 p[4];
#pragma unroll
    for (int i = 0; i < 4; ++i) p[i] = row4[lane + 64 * i];  // elem e = 256i+4*lane+c

    float v1 = -1e30f, v2 = -1e30f; int i1 = 0x7fffffff, i2 = 0x7fffffff;
#pragma unroll
    for (int i = 0; i < 4; ++i) {
        const float vv[4] = {p[i].x, p[i].y, p[i].z, p[i].w};
#pragma unroll
        for (int c = 0; c < 4; ++c) {
            const int e = 256 * i + 4 * lane + c;
            const float v = vv[c];
            if (better(v, e, v1, i1)) { v2 = v1; i2 = i1; v1 = v; i1 = e; }
            else if (better(v, e, v2, i2)) { v2 = v; i2 = e; }
        }
    }
#pragma unroll
    for (int off = 32; off; off >>= 1) {
        const float ov1 = __shfl_xor(v1, off); const int oi1 = __shfl_xor(i1, off);
        const float ov2 = __shfl_xor(v2, off); const int oi2 = __shfl_xor(i2, off);
        if (better(ov1, oi1, v1, i1)) {
            float nv2; int ni2;
            if (better(v1, i1, ov2, oi2)) { nv2 = v1; ni2 = i1; }
            else { nv2 = ov2; ni2 = oi2; }
            v1 = ov1; i1 = oi1; v2 = nv2; i2 = ni2;
        } else if (better(ov1, oi1, v2, i2)) { v2 = ov1; i2 = oi1; }
    }
    const float m = v1;   // top1 value IS the row max

    float s = 0.f;
#pragma unroll
    for (int i = 0; i < 4; ++i) {
        p[i].x = __expf(p[i].x - m); p[i].y = __expf(p[i].y - m);
        p[i].z = __expf(p[i].z - m); p[i].w = __expf(p[i].w - m);
        s += p[i].x + p[i].y + p[i].z + p[i].w;
    }
#pragma unroll
    for (int off = 32; off; off >>= 1) s += __shfl_xor(s, off);
    const float inv = 1.f / s;

#pragma unroll
    for (int i = 0; i < 4; ++i) {
        float4 q = make_float4(p[i].x * inv, p[i].y * inv, p[i].z * inv, p[i].w * inv);
        *(float4*)&L[w * 1024 + i * 256 + lane * 4] = q;
    }

    const float p1 = inv;                   // exp(v1-m)=1
    const float p2 = __expf(v2 - m) * inv;
    const int b = t >> 10;
    const float4* x1 = (const float4*)&X[((size_t)(b << 10) + i1) * ED];
    const float4* x2 = (const float4*)&X[((size_t)(b << 10) + i2) * ED];
    float4* yrow = (float4*)&OUT[(size_t)t * ED];
#pragma unroll
    for (int i = 0; i < 4; ++i) {
        const int idx = lane + 64 * i;
        const float4 a = x1[idx];
        const float4 c = x2[idx];
        float4 r;
        r.x = fmaf(p1, a.x, p2 * c.x);
        r.y = fmaf(p1, a.y, p2 * c.y);
        r.z = fmaf(p1, a.z, p2 * c.z);
        r.w = fmaf(p1, a.w, p2 * c.w);
        yrow[idx] = r;
    }

    if (lane == 0) { atomicAdd(&counts[i1], 1); atomicAdd(&counts[i2], 1); }

    __syncthreads();
    float4 s0 = *(float4*)&L[0 * 1024 + tid * 4];
    float4 s1 = *(float4*)&L[1 * 1024 + tid * 4];
    float4 s2 = *(float4*)&L[2 * 1024 + tid * 4];
    float4 s3 = *(float4*)&L[3 * 1024 + tid * 4];
    float4 r;
    r.x = (s0.x + s1.x) + (s2.x + s3.x);
    r.y = (s0.y + s1.y) + (s2.y + s3.y);
    r.z = (s0.z + s1.z) + (s2.z + s3.z);
    r.w = (s0.w + s1.w) + (s2.w + s3.w);
    *(float4*)&partial[(size_t)blockIdx.x * 1024 + tid * 4] = r;
}

// ---------------- aux: deterministic two-stage reduction ----------------
__global__ __launch_bounds__(256) void aux1_kernel(const float* __restrict__ partial,
                                                   const int* __restrict__ counts,
                                                   float* __restrict__ dotPartial) {
    __shared__ float red[16][16];
    const int tid = threadIdx.x;
    const int el  = tid & 15;
    const int ch  = tid >> 4;
    const int e   = blockIdx.x * 16 + el;
    float s = 0.f;
    for (int k = 0; k < 128; ++k)
        s += partial[(size_t)(ch * 128 + k) * 1024 + e];
    red[ch][el] = s;
    __syncthreads();
    if (tid < 16) {
        float rs = 0.f;
#pragma unroll
        for (int c = 0; c < 16; ++c) rs += red[c][tid];
        float val = rs * (float)counts[blockIdx.x * 16 + tid];
#pragma unroll
        for (int off = 8; off; off >>= 1) val += __shfl_xor(val, off);
        if (tid == 0) dotPartial[blockIdx.x] = val;
    }
}

__global__ void aux2_kernel(const float* __restrict__ dotPartial, float* __restrict__ out) {
    const int lane = threadIdx.x;
    float v = dotPartial[lane];
#pragma unroll
    for (int off = 32; off; off >>= 1) v += __shfl_xor(v, off);
    if (lane == 0)
        out[(size_t)MTOK * ED] = v * (0.01f * 1024.f / (8192.f * 16384.f));
}

// ---------------- fallback softmax (proven round-1 path) ----------------
#define TOKS_PER_BLK 16
__global__ __launch_bounds__(256) void softmax_topk_y_kernel(
        const float* __restrict__ X, float* __restrict__ OUT,
        float* __restrict__ router_sum, int* __restrict__ counts) {
    __shared__ float routerLocal[ED];
    __shared__ float redMax[4];
    __shared__ float redSum[4];
    __shared__ float wV1[4]; __shared__ int wI1[4];
    __shared__ float wV2[4]; __shared__ int wI2[4];

    const int tid  = threadIdx.x;
    const int lane = tid & 63;
    const int wave = tid >> 6;

    for (int e = tid; e < ED; e += 256) routerLocal[e] = 0.f;
    __syncthreads();

    const int t0 = blockIdx.x * TOKS_PER_BLK;
    for (int t = t0; t < t0 + TOKS_PER_BLK; ++t) {
        const float* lrow = &OUT[(size_t)t * ED];
        float l[4];
#pragma unroll
        for (int i = 0; i < 4; ++i) l[i] = lrow[tid + i * 256];

        float m = fmaxf(fmaxf(l[0], l[1]), fmaxf(l[2], l[3]));
#pragma unroll
        for (int off = 32; off; off >>= 1) m = fmaxf(m, __shfl_xor(m, off));
        if (lane == 0) redMax[wave] = m;
        __syncthreads();
        m = fmaxf(fmaxf(redMax[0], redMax[1]), fmaxf(redMax[2], redMax[3]));

        float p[4]; float s = 0.f;
#pragma unroll
        for (int i = 0; i < 4; ++i) { p[i] = expf(l[i] - m); s += p[i]; }
#pragma unroll
        for (int off = 32; off; off >>= 1) s += __shfl_xor(s, off);
        if (lane == 0) redSum[wave] = s;

        float v1 = -1e30f, v2 = -1e30f; int i1 = 0x7fffffff, i2 = 0x7fffffff;
#pragma unroll
        for (int i = 0; i < 4; ++i) {
            const float v = l[i]; const int ix = tid + i * 256;
            if (better(v, ix, v1, i1)) { v2 = v1; i2 = i1; v1 = v; i1 = ix; }
            else if (better(v, ix, v2, i2)) { v2 = v; i2 = ix; }
        }
#pragma unroll
        for (int off = 32; off; off >>= 1) {
            const float ov1 = __shfl_xor(v1, off); const int oi1 = __shfl_xor(i1, off);
            const float ov2 = __shfl_xor(v2, off); const int oi2 = __shfl_xor(i2, off);
            if (better(ov1, oi1, v1, i1)) {
                float nv2; int ni2;
                if (better(v1, i1, ov2, oi2)) { nv2 = v1; ni2 = i1; }
                else { nv2 = ov2; ni2 = oi2; }
                v1 = ov1; i1 = oi1; v2 = nv2; i2 = ni2;
            } else if (better(ov1, oi1, v2, i2)) { v2 = ov1; i2 = oi1; }
        }
        if (lane == 0) { wV1[wave] = v1; wI1[wave] = i1; wV2[wave] = v2; wI2[wave] = i2; }
        __syncthreads();

        v1 = wV1[0]; i1 = wI1[0]; v2 = wV2[0]; i2 = wI2[0];
#pragma unroll
        for (int w = 1; w < 4; ++w) {
            const float ov1 = wV1[w]; const int oi1 = wI1[w];
            const float ov2 = wV2[w]; const int oi2 = wI2[w];
            if (better(ov1, oi1, v1, i1)) {
                float nv2; int ni2;
                if (better(v1, i1, ov2, oi2)) { nv2 = v1; ni2 = i1; }
                else { nv2 = ov2; ni2 = oi2; }
                v1 = ov1; i1 = oi1; v2 = nv2; i2 = ni2;
            } else if (better(ov1, oi1, v2, i2)) { v2 = ov1; i2 = oi1; }
        }
        const float stot = redSum[0] + redSum[1] + redSum[2] + redSum[3];
        const float inv = 1.f / stot;

#pragma unroll
        for (int i = 0; i < 4; ++i) routerLocal[tid + i * 256] += p[i] * inv;

        const float p1 = expf(v1 - m) * inv;
        const float p2 = expf(v2 - m) * inv;

        const int b = t >> 10;
        const float4* x1 = (const float4*)&X[((size_t)(b << 10) + i1) * ED];
        const float4* x2 = (const float4*)&X[((size_t)(b << 10) + i2) * ED];
        float4* yrow = (float4*)&OUT[(size_t)t * ED];
        const float4 a = x1[tid];
        const float4 c = x2[tid];
        float4 r;
        r.x = fmaf(p1, a.x, p2 * c.x);
        r.y = fmaf(p1, a.y, p2 * c.y);
        r.z = fmaf(p1, a.z, p2 * c.z);
        r.w = fmaf(p1, a.w, p2 * c.w);
        yrow[tid] = r;

        if (tid == 0) { atomicAdd(&counts[i1], 1); atomicAdd(&counts[i2], 1); }
        __syncthreads();
    }

    for (int e = tid; e < ED; e += 256) atomicAdd(&router_sum[e], routerLocal[e]);
}

__global__ __launch_bounds__(256) void aux_kernel(const float* __restrict__ router_sum,
                                                  const int* __restrict__ counts,
                                                  float* __restrict__ out) {
    __shared__ float red[4];
    const int tid = threadIdx.x;
    float s = 0.f;
    for (int e = tid; e < ED; e += 256)
        s += (router_sum[e] * (1.f / 8192.f)) * ((float)counts[e] * (1.f / 16384.f));
#pragma unroll
    for (int off = 32; off; off >>= 1) s += __shfl_xor(s, off);
    if ((tid & 63) == 0) red[tid >> 6] = s;
    __syncthreads();
    if (tid == 0) out[(size_t)MTOK * ED] = 0.01f * 1024.f * (red[0] + red[1] + red[2] + red[3]);
}

// ---------------- launch ----------------
extern "C" void kernel_launch(void* const* d_in, const int* in_sizes, int n_in,
                              void* d_out, int out_size, void* d_ws, size_t ws_size,
                              hipStream_t stream) {
    const float* X = (const float*)d_in[0];   // (B,S,D) fp32
    const float* W = (const float*)d_in[1];   // (E,D)  fp32
    float* out = (float*)d_out;

    const size_t WS_NEED = (size_t)ED * ED * 2 * sizeof(unsigned short)   // Bhi,Blo 4MB
                         + (size_t)2048 * 1024 * sizeof(float)            // partial 8MB
                         + 64 * sizeof(float) + ED * sizeof(int);

    if (ws_size >= WS_NEED) {
        unsigned short* Bhi = (unsigned short*)d_ws;
        unsigned short* Blo = Bhi + (size_t)ED * ED;
        float* partial      = (float*)(Blo + (size_t)ED * ED);   // [2048][1024]
        float* dotPartial   = partial + (size_t)2048 * 1024;     // 64 floats
        int*   counts       = (int*)(dotPartial + 64);           // 1024 ints

        hipMemsetAsync(counts, 0, ED * sizeof(int), stream);
        wfrag_kernel<<<512, 256, 0, stream>>>(W, Bhi, Blo);
        gemm_mfma_split_kernel<<<512, 256, 0, stream>>>(X, Bhi, Blo, out);
        softmax_wave_kernel<<<MTOK / 4, 256, 0, stream>>>(X, out, partial, counts);
        aux1_kernel<<<64, 256, 0, stream>>>(partial, counts, dotPartial);
        aux2_kernel<<<1, 64, 0, stream>>>(dotPartial, out);
    } else {
        float* router_sum = (float*)d_ws;
        int*   counts     = (int*)((char*)d_ws + ED * sizeof(float));
        hipMemsetAsync(d_ws, 0, ED * (sizeof(float) + sizeof(int)), stream);
        dim3 ggrid(ED / BN, MTOK / BM);
        gemm_logits_kernel<<<ggrid, 256, 0, stream>>>(X, W, out);
        softmax_topk_y_kernel<<<MTOK / TOKS_PER_BLK, 256, 0, stream>>>(X, out, router_sum, counts);
        aux_kernel<<<1, 256, 0, stream>>>(router_sum, counts, out);
    }
}